// Round 2
// baseline (786.347 us; speedup 1.0000x reference)
//
#include <hip/hip_runtime.h>
#include <stdint.h>

#define MM 4096   // B*S
#define KK 4096   // IN_F
#define NN 11008  // OUT_F
#define NK 64     // KK/64 K-steps of the 256^2 kernel

typedef __bf16 bf16;
typedef bf16 bf16x8 __attribute__((ext_vector_type(8)));
typedef float f32x4 __attribute__((ext_vector_type(4)));

static_assert(sizeof(bf16x8) == 16, "bf16x8 must be 16B");

// ---------------- async global->LDS (width 16) ----------------
__device__ __forceinline__ void async_ld16(const void* g, void* l) {
  __builtin_amdgcn_global_load_lds(
      (const __attribute__((address_space(1))) uint32_t*)g,
      (__attribute__((address_space(3))) uint32_t*)l,
      16, 0, 0);
}

// ---------------- convert kernels ----------------
__global__ __launch_bounds__(256) void cvt_a_kernel(const float* __restrict__ in,
                                                    bf16* __restrict__ out, int n4) {
  int i = blockIdx.x * 256 + threadIdx.x;
  if (i >= n4) return;
  float4 v = ((const float4*)in)[i];
  union { bf16 h[4]; uint2 u; } p;
  p.h[0] = (bf16)v.x; p.h[1] = (bf16)v.y; p.h[2] = (bf16)v.z; p.h[3] = (bf16)v.w;
  ((uint2*)out)[i] = p.u;
}

// weights land as int32 (harness integer contract; confirmed earlier: absmax=256 path passes).
__global__ __launch_bounds__(256) void cvt_w_kernel(const int* __restrict__ in,
                                                    bf16* __restrict__ out, int n4) {
  int i = blockIdx.x * 256 + threadIdx.x;
  if (i >= n4) return;
  int4 v = ((const int4*)in)[i];
  union { bf16 h[4]; uint2 u; } p;
  p.h[0] = (bf16)(float)v.x; p.h[1] = (bf16)(float)v.y;
  p.h[2] = (bf16)(float)v.z; p.h[3] = (bf16)(float)v.w;
  ((uint2*)out)[i] = p.u;
}

// =====================================================================
// 256x256 8-phase GEMM (m201 template: T1+T2+T3+T4+T5)
//
// Geometry: BM=BN=256, BK=64, 512 thr = 8 waves (2M x 4N), per-wave C =
// 128x64 = acc[8][4] f32x4. LDS = 2 dbuf x (A 256x64 + B 256x64) bf16 =
// 128 KiB (dynamic). 16 MFMA (16x16x32) per phase, 4 phases per K-step.
//
// T2 swizzle, CORRECTED (R1 post-mortem): for ds_read_b128, the row term
// (lane&15)*128B is =0 mod 128B, so bank position is pos = kc*4 +
// (lane>>4); R0's XOR of byte bit 5 permuted lanes WITHIN one 64B kc-half
// -> still 4 positions x 16 lanes = 2x bank serialization (3.38e7
// conflicts, MfmaUtil 38%). Fix flips byte bit 6 (64B, crosses the
// kc-half) keyed on row bit 0 (= lane bit 0, varies within each 16-lane
// group):   content[R][e] = global[R][e ^ 32*(R&1)]   (elements)
//   - write: global_load_lds dest LINEAR; thread tid writes row tid>>3
//     (row bit0 = tid bit3) -> source pre-swizzle t2 = tid^4 when tid&8.
//   - read: element offset ((kc*32) ^ (lane&1)*32) + (lane>>4)*8.
// pos = (kc*4 + (lane>>4)) ^ 4*(lane&1): 8 positions x 8 lanes = each
// bank hit exactly 8x per b128 = conflict-free minimum.
//
// Stage schedule per K-step c (race-free; verified R0/R1 pass):
//   p0: Q0 reads A m0-3, B n0-1 ; stage (c+1).B1 [other buf]
//   p1: Q1 reads B n2-3         ; stage (c+1).A1 [other buf]
//   p2: Q2 reads A m4-7         ; stage (c+2).B0 [this buf; B0 reads
//        drained by p1 lgkm0 + p1 end-barrier before this issue]
//   p3: Q3 no reads             ; stage (c+2).A0 [this buf; A0 reads
//        drained by p2 lgkm0 + p2 end-barrier]
//   boundary: vmcnt(4) -> all of (c+1) landed, (c+2).B0/A0 in flight.
// =====================================================================
__global__ __launch_bounds__(512, 2) void gemm256_kernel(
    const bf16* __restrict__ A,   // [MM][KK] bf16
    const bf16* __restrict__ W,   // [NN][KK] bf16 (B^T layout)
    const float* __restrict__ scales,
    const float* __restrict__ bias,
    float* __restrict__ out) {
  extern __shared__ bf16 lds[];
  bf16* LA = lds;               // [2][256][64]
  bf16* LB = lds + 2 * 16384;   // [2][256][64]

  const int tid  = threadIdx.x;
  const int lane = tid & 63;
  const int wave = tid >> 6;          // 0..7
  const int wr   = wave >> 2;         // 0..1  (M half)
  const int wc   = wave & 3;          // 0..3  (N quarter)

  // T1: bijective XCD swizzle. nwg = 16*43 = 688 = 8*86 exactly.
  const int flat = blockIdx.y * 16 + blockIdx.x;
  const int swz  = (flat & 7) * 86 + (flat >> 3);
  const int bm   = swz & 15;   // 0..15
  const int bn   = swz >> 4;   // 0..42

  // staging source mapping (inverse of the corrected T2 swizzle)
  const int t2   = (tid & 8) ? (tid ^ 4) : tid;
  const int srow = tid >> 3;           // 0..63 (row within a 64-row issue)
  const int skel = (t2 & 7) * 8;       // pre-swizzled k element
  const bf16* gA = A + (size_t)(bm * 256 + srow) * KK + skel;
  const bf16* gW = W + (size_t)(bn * 256 + srow) * KK + skel;

  // ds_read per-lane offsets (corrected T2 swizzle)
  const int m16   = lane & 15;
  const int kbase = (lane >> 4) * 8;
  const int kxor  = (lane & 1) * 32;
  const int ke0   = kxor + kbase;          // logical kc=0
  const int ke1   = (32 ^ kxor) + kbase;   // logical kc=1
  const int aRow  = wr * 128 + m16;
  const int bRow  = wc * 64 + m16;

  f32x4 acc[8][4] = {};

  // ---- prologue: K0 fully + K1 first 2 half-tiles ----
  auto stage_half = [&](const bf16* g, bf16* l) {
    async_ld16(g, l + wave * 512);
    async_ld16(g + (size_t)64 * KK, l + 64 * 64 + wave * 512);
  };
  stage_half(gW,                    LB);             // K0.B0
  stage_half(gA,                    LA);             // K0.A0
  stage_half(gW + (size_t)128 * KK, LB + 128 * 64);  // K0.B1
  stage_half(gA + (size_t)128 * KK, LA + 128 * 64);  // K0.A1
  stage_half(gW + 64,               LB + 16384);     // K1.B0
  stage_half(gA + 64,               LA + 16384);     // K1.A0
  asm volatile("s_waitcnt vmcnt(4)" ::: "memory");   // K0 landed; K1.B0/A0 in flight
  __builtin_amdgcn_s_barrier();

  for (int c = 0; c < NK; ++c) {
    const int cb = c & 1;
    const bf16* At = LA + cb * 16384;          // K-step c (read)
    const bf16* Wt = LB + cb * 16384;
    bf16* An = LA + (cb ^ 1) * 16384;          // K-step c+1 (stage)
    bf16* Bn = LB + (cb ^ 1) * 16384;
    bf16* Ac = LA + cb * 16384;                // K-step c+2 (stage, same buf as read)
    bf16* Bc = LB + cb * 16384;
    const size_t k1 = (size_t)(c + 1) * 64;
    const size_t k2 = (size_t)(c + 2) * 64;

    bf16x8 aLo[4][2], aHi[4][2], bLo[2][2], bHi[2][2];

    // ---------- phase 0: Q0 = m0-3 x n0-1 ----------
#pragma unroll
    for (int fm = 0; fm < 4; ++fm) {
      aLo[fm][0] = *(const bf16x8*)(At + (aRow + fm * 16) * 64 + ke0);
      aLo[fm][1] = *(const bf16x8*)(At + (aRow + fm * 16) * 64 + ke1);
    }
#pragma unroll
    for (int fn = 0; fn < 2; ++fn) {
      bLo[fn][0] = *(const bf16x8*)(Wt + (bRow + fn * 16) * 64 + ke0);
      bLo[fn][1] = *(const bf16x8*)(Wt + (bRow + fn * 16) * 64 + ke1);
    }
    if (c + 1 < NK) stage_half(gW + (size_t)128 * KK + k1, Bn + 128 * 64);  // (c+1).B1
    __builtin_amdgcn_s_barrier();
    asm volatile("s_waitcnt lgkmcnt(0)" ::: "memory");
    __builtin_amdgcn_s_setprio(1);
#pragma unroll
    for (int fm = 0; fm < 4; ++fm)
#pragma unroll
      for (int fn = 0; fn < 2; ++fn)
#pragma unroll
        for (int kc = 0; kc < 2; ++kc)
          acc[fm][fn] = __builtin_amdgcn_mfma_f32_16x16x32_bf16(aLo[fm][kc], bLo[fn][kc], acc[fm][fn], 0, 0, 0);
    __builtin_amdgcn_s_setprio(0);
    __builtin_amdgcn_s_barrier();

    // ---------- phase 1: Q1 = m0-3 x n2-3 ----------
#pragma unroll
    for (int fn = 0; fn < 2; ++fn) {
      bHi[fn][0] = *(const bf16x8*)(Wt + (bRow + (fn + 2) * 16) * 64 + ke0);
      bHi[fn][1] = *(const bf16x8*)(Wt + (bRow + (fn + 2) * 16) * 64 + ke1);
    }
    if (c + 1 < NK) stage_half(gA + (size_t)128 * KK + k1, An + 128 * 64);  // (c+1).A1
    __builtin_amdgcn_s_barrier();
    asm volatile("s_waitcnt lgkmcnt(0)" ::: "memory");
    __builtin_amdgcn_s_setprio(1);
#pragma unroll
    for (int fm = 0; fm < 4; ++fm)
#pragma unroll
      for (int fn = 0; fn < 2; ++fn)
#pragma unroll
        for (int kc = 0; kc < 2; ++kc)
          acc[fm][fn + 2] = __builtin_amdgcn_mfma_f32_16x16x32_bf16(aLo[fm][kc], bHi[fn][kc], acc[fm][fn + 2], 0, 0, 0);
    __builtin_amdgcn_s_setprio(0);
    __builtin_amdgcn_s_barrier();

    // ---------- phase 2: Q2 = m4-7 x n0-1 ----------
#pragma unroll
    for (int fm = 0; fm < 4; ++fm) {
      aHi[fm][0] = *(const bf16x8*)(At + (aRow + (fm + 4) * 16) * 64 + ke0);
      aHi[fm][1] = *(const bf16x8*)(At + (aRow + (fm + 4) * 16) * 64 + ke1);
    }
    if (c + 2 < NK) stage_half(gW + k2, Bc);                                // (c+2).B0
    __builtin_amdgcn_s_barrier();
    asm volatile("s_waitcnt lgkmcnt(0)" ::: "memory");
    __builtin_amdgcn_s_setprio(1);
#pragma unroll
    for (int fm = 0; fm < 4; ++fm)
#pragma unroll
      for (int fn = 0; fn < 2; ++fn)
#pragma unroll
        for (int kc = 0; kc < 2; ++kc)
          acc[fm + 4][fn] = __builtin_amdgcn_mfma_f32_16x16x32_bf16(aHi[fm][kc], bLo[fn][kc], acc[fm + 4][fn], 0, 0, 0);
    __builtin_amdgcn_s_setprio(0);
    __builtin_amdgcn_s_barrier();

    // ---------- phase 3: Q3 = m4-7 x n2-3 ----------
    if (c + 2 < NK) stage_half(gA + k2, Ac);                                // (c+2).A0
    __builtin_amdgcn_s_barrier();
    __builtin_amdgcn_s_setprio(1);
#pragma unroll
    for (int fm = 0; fm < 4; ++fm)
#pragma unroll
      for (int fn = 0; fn < 2; ++fn)
#pragma unroll
        for (int kc = 0; kc < 2; ++kc)
          acc[fm + 4][fn + 2] = __builtin_amdgcn_mfma_f32_16x16x32_bf16(aHi[fm][kc], bHi[fn][kc], acc[fm + 4][fn + 2], 0, 0, 0);
    __builtin_amdgcn_s_setprio(0);
    // K-step boundary: counted wait (T4). Never 0 except at the tail.
    if (c + 2 < NK) asm volatile("s_waitcnt vmcnt(4)" ::: "memory");
    else            asm volatile("s_waitcnt vmcnt(0)" ::: "memory");
    __builtin_amdgcn_s_barrier();
  }

  // ---------- epilogue ----------
  const int row0 = bm * 256 + wr * 128 + ((lane >> 4) * 4);
  const int col0 = bn * 256 + wc * 64 + (lane & 15);
#pragma unroll
  for (int fn = 0; fn < 4; ++fn) {
    const int col = col0 + fn * 16;
    const float s = scales[col];
    const float b = bias[col];
#pragma unroll
    for (int fm = 0; fm < 8; ++fm) {
      const int r0 = row0 + fm * 16;
#pragma unroll
      for (int r = 0; r < 4; ++r)
        out[(size_t)(r0 + r) * NN + col] = acc[fm][fn][r] * s + b;
    }
  }
}

// ---------------- fallback: fused convert-in-staging (if ws too small) ----------------
__device__ __forceinline__ void epilogue128(f32x4 acc[4][4],
                                            const float* __restrict__ scales,
                                            const float* __restrict__ bias,
                                            float* __restrict__ out,
                                            int bm, int bn, int lane, int wr, int wc) {
  const int row0 = bm * 128 + wr * 64 + ((lane >> 4) * 4);
  const int col0 = bn * 128 + wc * 64 + (lane & 15);
#pragma unroll
  for (int tn = 0; tn < 4; ++tn) {
    const int col = col0 + tn * 16;
    const float s = scales[col];
    const float b = bias[col];
#pragma unroll
    for (int tm = 0; tm < 4; ++tm) {
      const int r0 = row0 + tm * 16;
#pragma unroll
      for (int r = 0; r < 4; ++r)
        out[(long)(r0 + r) * NN + col] = acc[tm][tn][r] * s + b;
    }
  }
}

__global__ __launch_bounds__(256, 2) void gemm_fused_kernel(
    const float* __restrict__ A,   // [MM][KK] fp32
    const int* __restrict__ W32,   // [NN][KK] int32
    const float* __restrict__ scales,
    const float* __restrict__ bias,
    float* __restrict__ out) {
  __shared__ bf16 As[128 * 32];
  __shared__ bf16 Ws[128 * 32];
  const int tid  = threadIdx.x;
  const int lane = tid & 63;
  const int wave = tid >> 6;
  const int wr   = wave >> 1, wc = wave & 1;
  const int bm   = blockIdx.x, bn = blockIdx.y;

  f32x4 acc[4][4] = {};

  const int r    = tid >> 1;
  const int kk16 = (tid & 1) * 16;

  const float* Ag = A + (long)(bm * 128 + r) * KK + kk16;
  const int*   Wg = W32 + (long)(bn * 128 + r) * KK + kk16;
  bf16* Asw = As + r * 32 + kk16;
  bf16* Wsw = Ws + r * 32 + kk16;

  for (int k0 = 0; k0 < KK; k0 += 32) {
    float4 a0 = *(const float4*)(Ag + k0);
    float4 a1 = *(const float4*)(Ag + k0 + 4);
    float4 a2 = *(const float4*)(Ag + k0 + 8);
    float4 a3 = *(const float4*)(Ag + k0 + 12);
    int4 v0 = *(const int4*)(Wg + k0);
    int4 v1 = *(const int4*)(Wg + k0 + 4);
    int4 v2 = *(const int4*)(Wg + k0 + 8);
    int4 v3 = *(const int4*)(Wg + k0 + 12);
    __syncthreads();
    bf16x8 h0, h1, w0, w1;
    h0[0] = (bf16)a0.x; h0[1] = (bf16)a0.y; h0[2] = (bf16)a0.z; h0[3] = (bf16)a0.w;
    h0[4] = (bf16)a1.x; h0[5] = (bf16)a1.y; h0[6] = (bf16)a1.z; h0[7] = (bf16)a1.w;
    h1[0] = (bf16)a2.x; h1[1] = (bf16)a2.y; h1[2] = (bf16)a2.z; h1[3] = (bf16)a2.w;
    h1[4] = (bf16)a3.x; h1[5] = (bf16)a3.y; h1[6] = (bf16)a3.z; h1[7] = (bf16)a3.w;
    w0[0] = (bf16)(float)v0.x; w0[1] = (bf16)(float)v0.y;
    w0[2] = (bf16)(float)v0.z; w0[3] = (bf16)(float)v0.w;
    w0[4] = (bf16)(float)v1.x; w0[5] = (bf16)(float)v1.y;
    w0[6] = (bf16)(float)v1.z; w0[7] = (bf16)(float)v1.w;
    w1[0] = (bf16)(float)v2.x; w1[1] = (bf16)(float)v2.y;
    w1[2] = (bf16)(float)v2.z; w1[3] = (bf16)(float)v2.w;
    w1[4] = (bf16)(float)v3.x; w1[5] = (bf16)(float)v3.y;
    w1[6] = (bf16)(float)v3.z; w1[7] = (bf16)(float)v3.w;
    *(bf16x8*)(Asw)     = h0;
    *(bf16x8*)(Asw + 8) = h1;
    *(bf16x8*)(Wsw)     = w0;
    *(bf16x8*)(Wsw + 8) = w1;
    __syncthreads();
    const int m16 = lane & 15;
    const int ko  = (lane >> 4) * 8;
    bf16x8 af[4], bg[4];
#pragma unroll
    for (int t = 0; t < 4; ++t) {
      af[t] = *(const bf16x8*)(As + (wr * 64 + t * 16 + m16) * 32 + ko);
      bg[t] = *(const bf16x8*)(Ws + (wc * 64 + t * 16 + m16) * 32 + ko);
    }
#pragma unroll
    for (int tm = 0; tm < 4; ++tm)
#pragma unroll
      for (int tn = 0; tn < 4; ++tn)
        acc[tm][tn] = __builtin_amdgcn_mfma_f32_16x16x32_bf16(af[tm], bg[tn], acc[tm][tn], 0, 0, 0);
  }
  epilogue128(acc, scales, bias, out, bm, bn, lane, wr, wc);
}

// ---------------- launch ----------------
extern "C" void kernel_launch(void* const* d_in, const int* in_sizes, int n_in,
                              void* d_out, int out_size, void* d_ws, size_t ws_size,
                              hipStream_t stream) {
  const float* x      = (const float*)d_in[0];
  const int*   w32    = (const int*)d_in[1];
  const float* scales = (const float*)d_in[2];
  const float* bias   = (const float*)d_in[3];
  float*       out    = (float*)d_out;

  const size_t A_BYTES = (size_t)MM * KK * 2;  // 32 MiB
  const size_t W_BYTES = (size_t)NN * KK * 2;  // 86 MiB

  if (ws_size >= A_BYTES + W_BYTES) {
    static bool attr_done = false;
    if (!attr_done) {
      (void)hipFuncSetAttribute((const void*)gemm256_kernel,
                                hipFuncAttributeMaxDynamicSharedMemorySize, 131072);
      attr_done = true;
    }
    bf16* A16 = (bf16*)d_ws;
    bf16* W16 = (bf16*)((char*)d_ws + A_BYTES);
    const int na = MM * KK / 4;
    hipLaunchKernelGGL(cvt_a_kernel, dim3((na + 255) / 256), dim3(256), 0, stream, x, A16, na);
    const int nw = NN * KK / 4;
    hipLaunchKernelGGL(cvt_w_kernel, dim3((nw + 255) / 256), dim3(256), 0, stream, w32, W16, nw);
    hipLaunchKernelGGL(gemm256_kernel, dim3(MM / 256, NN / 256), dim3(512), 131072, stream,
                       A16, W16, scales, bias, out);
  } else {
    hipLaunchKernelGGL(gemm_fused_kernel, dim3(MM / 128, NN / 128), dim3(256), 0, stream,
                       x, w32, scales, bias, out);
  }
}

// Round 3
// 685.368 us; speedup vs baseline: 1.1473x; 1.1473x over previous
//
#include <hip/hip_runtime.h>
#include <stdint.h>

#define MM 4096   // B*S
#define KK 4096   // IN_F
#define NN 11008  // OUT_F
#define NK 64     // KK/64 K-steps of the 256^2 kernel

typedef __bf16 bf16;
typedef bf16 bf16x8 __attribute__((ext_vector_type(8)));
typedef float f32x4 __attribute__((ext_vector_type(4)));

static_assert(sizeof(bf16x8) == 16, "bf16x8 must be 16B");

// ---------------- async global->LDS (width 16) ----------------
__device__ __forceinline__ void async_ld16(const void* g, void* l) {
  __builtin_amdgcn_global_load_lds(
      (const __attribute__((address_space(1))) uint32_t*)g,
      (__attribute__((address_space(3))) uint32_t*)l,
      16, 0, 0);
}

// ---------------- convert kernels ----------------
__global__ __launch_bounds__(256) void cvt_a_kernel(const float* __restrict__ in,
                                                    bf16* __restrict__ out, int n4) {
  int i = blockIdx.x * 256 + threadIdx.x;
  if (i >= n4) return;
  float4 v = ((const float4*)in)[i];
  union { bf16 h[4]; uint2 u; } p;
  p.h[0] = (bf16)v.x; p.h[1] = (bf16)v.y; p.h[2] = (bf16)v.z; p.h[3] = (bf16)v.w;
  ((uint2*)out)[i] = p.u;
}

// weights land as int32 (harness integer contract; absmax=256 path passes).
__global__ __launch_bounds__(256) void cvt_w_kernel(const int* __restrict__ in,
                                                    bf16* __restrict__ out, int n4) {
  int i = blockIdx.x * 256 + threadIdx.x;
  if (i >= n4) return;
  int4 v = ((const int4*)in)[i];
  union { bf16 h[4]; uint2 u; } p;
  p.h[0] = (bf16)(float)v.x; p.h[1] = (bf16)(float)v.y;
  p.h[2] = (bf16)(float)v.z; p.h[3] = (bf16)(float)v.w;
  ((uint2*)out)[i] = p.u;
}

// =====================================================================
// 256x256 GEMM, 2-barrier K-step (R3 restructure of the m201 template)
//
// R2 POST-MORTEM: row-bit0-keyed swizzle TRIPLED conflicts (1.01e8 ~= the
// unswizzled rate). REVERTED to R1's verbatim st_16x32 (m201 spec:
// byte ^= ((byte>>9)&1)<<5): read kk = ((lane>>4)*8)^(((lane>>2)&1)*16),
// write source pre-swizzle t2 = tid^2 when tid&32. Measured best
// (3.38e7 conflicts, 426us).
//
// R3 CHANGE (sync structure): 8 barriers/K-step -> 2.
//   - all 24 ds_read_b128 issued at top of K-step (aLo,bLo,bHi,aHi);
//     compiler inserts exact counted lgkmcnt before each MFMA group, so
//     q0 (needs first 12) starts while the other 12 drain under MFMA.
//   - stage (c+1).B1/A1 [other buffer] right after the reads.
//   - q0,q1 MFMAs.
//   - lgkmcnt(0) + raw s_barrier  == "all waves done reading buffer c"
//     (raw barrier keeps vmcnt in flight; __syncthreads would drain it).
//   - stage (c+2).B0/A0 [this buffer - now safe to overwrite].
//   - q2,q3 MFMAs (registers only).
//   - boundary vmcnt(4): oldest 4 of 8 outstanding = (c+1).B1/A1 landed;
//     (c+2).B0/A0 stay in flight. s_barrier.
// Hazards audited: (c+1) other-buf stages safe after PREVIOUS mid-barrier;
// (c+2) same-buf stages safe after THIS mid-barrier; (c+1) residency at
// its read time guaranteed by boundary vmcnt(4) of step c (oldest-first
// ordering). Tail: last two K-steps peeled (branch-free hot loop, exact
// waitcnt counting); NK-2 boundary uses vmcnt(0) to land (NK-1).B1/A1.
// =====================================================================
__global__ __launch_bounds__(512, 2) void gemm256_kernel(
    const bf16* __restrict__ A,   // [MM][KK] bf16
    const bf16* __restrict__ W,   // [NN][KK] bf16 (B^T layout)
    const float* __restrict__ scales,
    const float* __restrict__ bias,
    float* __restrict__ out) {
  extern __shared__ bf16 lds[];
  bf16* LA = lds;               // [2][256][64]
  bf16* LB = lds + 2 * 16384;   // [2][256][64]

  const int tid  = threadIdx.x;
  const int lane = tid & 63;
  const int wave = tid >> 6;          // 0..7
  const int wr   = wave >> 2;         // 0..1  (M half)
  const int wc   = wave & 3;          // 0..3  (N quarter)

  // T1: bijective XCD swizzle. nwg = 16*43 = 688 = 8*86 exactly.
  const int flat = blockIdx.y * 16 + blockIdx.x;
  const int swz  = (flat & 7) * 86 + (flat >> 3);
  const int bm   = swz & 15;   // 0..15
  const int bn   = swz >> 4;   // 0..42

  // staging source mapping (inverse st_16x32 swizzle, R1 verbatim)
  const int t2   = (tid & 32) ? (tid ^ 2) : tid;
  const int srow = tid >> 3;           // 0..63 (row within a 64-row issue)
  const int skel = (t2 & 7) * 8;       // pre-swizzled k element
  const bf16* gA = A + (size_t)(bm * 256 + srow) * KK + skel;
  const bf16* gW = W + (size_t)(bn * 256 + srow) * KK + skel;

  // ds_read per-lane offsets (st_16x32, R1 verbatim)
  const int m16  = lane & 15;
  const int kk   = ((lane >> 4) * 8) ^ (((lane >> 2) & 1) * 16);
  const int aRow = wr * 128 + m16;
  const int bRow = wc * 64 + m16;

  f32x4 acc[8][4] = {};

  auto stage_half = [&](const bf16* g, bf16* l) {
    async_ld16(g, l + wave * 512);
    async_ld16(g + (size_t)64 * KK, l + 64 * 64 + wave * 512);
  };

  // ---- prologue: K0 fully + K1 first 2 half-tiles ----
  stage_half(gW,                    LB);             // K0.B0
  stage_half(gA,                    LA);             // K0.A0
  stage_half(gW + (size_t)128 * KK, LB + 128 * 64);  // K0.B1
  stage_half(gA + (size_t)128 * KK, LA + 128 * 64);  // K0.A1
  stage_half(gW + 64,               LB + 16384);     // K1.B0
  stage_half(gA + 64,               LA + 16384);     // K1.A0
  asm volatile("s_waitcnt vmcnt(4)" ::: "memory");   // K0 landed; K1.B0/A0 in flight
  __builtin_amdgcn_s_barrier();

  // ---- one K-step (s1: stage c+1 halves, s2: stage c+2 halves) ----
  auto kstep = [&](int c, bool s1, bool s2, bool tail) {
    const int cb = c & 1;
    const bf16* At = LA + cb * 16384;          // K-step c (read)
    const bf16* Wt = LB + cb * 16384;
    bf16* An = LA + (cb ^ 1) * 16384;          // K-step c+1 (stage, other buf)
    bf16* Bn = LB + (cb ^ 1) * 16384;
    bf16* Ac = LA + cb * 16384;                // K-step c+2 (stage, this buf)
    bf16* Bc = LB + cb * 16384;
    const size_t k1 = (size_t)(c + 1) * 64;
    const size_t k2 = (size_t)(c + 2) * 64;

    bf16x8 aLo[4][2], aHi[4][2], bLo[2][2], bHi[2][2];

    // all 24 fragment reads up front; compiler emits counted lgkmcnt
#pragma unroll
    for (int fm = 0; fm < 4; ++fm)
#pragma unroll
      for (int kc = 0; kc < 2; ++kc)
        aLo[fm][kc] = *(const bf16x8*)(At + (aRow + fm * 16) * 64 + kc * 32 + kk);
#pragma unroll
    for (int fn = 0; fn < 2; ++fn)
#pragma unroll
      for (int kc = 0; kc < 2; ++kc)
        bLo[fn][kc] = *(const bf16x8*)(Wt + (bRow + fn * 16) * 64 + kc * 32 + kk);
#pragma unroll
    for (int fn = 0; fn < 2; ++fn)
#pragma unroll
      for (int kc = 0; kc < 2; ++kc)
        bHi[fn][kc] = *(const bf16x8*)(Wt + (bRow + (fn + 2) * 16) * 64 + kc * 32 + kk);
#pragma unroll
    for (int fm = 0; fm < 4; ++fm)
#pragma unroll
      for (int kc = 0; kc < 2; ++kc)
        aHi[fm][kc] = *(const bf16x8*)(At + (aRow + (fm + 4) * 16) * 64 + kc * 32 + kk);

    if (s1) {
      stage_half(gW + (size_t)128 * KK + k1, Bn + 128 * 64);  // (c+1).B1
      stage_half(gA + (size_t)128 * KK + k1, An + 128 * 64);  // (c+1).A1
    }

    __builtin_amdgcn_s_setprio(1);
#pragma unroll
    for (int fm = 0; fm < 4; ++fm)        // q0: mLo x nLo
#pragma unroll
      for (int fn = 0; fn < 2; ++fn)
#pragma unroll
        for (int kc = 0; kc < 2; ++kc)
          acc[fm][fn] = __builtin_amdgcn_mfma_f32_16x16x32_bf16(aLo[fm][kc], bLo[fn][kc], acc[fm][fn], 0, 0, 0);
#pragma unroll
    for (int fm = 0; fm < 4; ++fm)        // q1: mLo x nHi
#pragma unroll
      for (int fn = 0; fn < 2; ++fn)
#pragma unroll
        for (int kc = 0; kc < 2; ++kc)
          acc[fm][fn + 2] = __builtin_amdgcn_mfma_f32_16x16x32_bf16(aLo[fm][kc], bHi[fn][kc], acc[fm][fn + 2], 0, 0, 0);
    __builtin_amdgcn_s_setprio(0);

    // all waves done reading buffer c (raw barrier: vmcnt stays in flight)
    asm volatile("s_waitcnt lgkmcnt(0)" ::: "memory");
    __builtin_amdgcn_s_barrier();

    if (s2) {
      stage_half(gW + k2, Bc);                                // (c+2).B0
      stage_half(gA + k2, Ac);                                // (c+2).A0
    }

    __builtin_amdgcn_s_setprio(1);
#pragma unroll
    for (int fm = 0; fm < 4; ++fm)        // q2: mHi x nLo
#pragma unroll
      for (int fn = 0; fn < 2; ++fn)
#pragma unroll
        for (int kc = 0; kc < 2; ++kc)
          acc[fm + 4][fn] = __builtin_amdgcn_mfma_f32_16x16x32_bf16(aHi[fm][kc], bLo[fn][kc], acc[fm + 4][fn], 0, 0, 0);
#pragma unroll
    for (int fm = 0; fm < 4; ++fm)        // q3: mHi x nHi
#pragma unroll
      for (int fn = 0; fn < 2; ++fn)
#pragma unroll
        for (int kc = 0; kc < 2; ++kc)
          acc[fm + 4][fn + 2] = __builtin_amdgcn_mfma_f32_16x16x32_bf16(aHi[fm][kc], bHi[fn][kc], acc[fm + 4][fn + 2], 0, 0, 0);
    __builtin_amdgcn_s_setprio(0);

    // K-step boundary: counted wait (T4); vmcnt(0) only at the tail.
    if (!tail) asm volatile("s_waitcnt vmcnt(4)" ::: "memory");
    else       asm volatile("s_waitcnt vmcnt(0)" ::: "memory");
    __builtin_amdgcn_s_barrier();
  };

  for (int c = 0; c < NK - 2; ++c) kstep(c, true, true, false);
  kstep(NK - 2, true, false, true);   // vmcnt(0): (NK-1).B1/A1 must land
  kstep(NK - 1, false, false, true);

  // ---------- epilogue ----------
  const int row0 = bm * 256 + wr * 128 + ((lane >> 4) * 4);
  const int col0 = bn * 256 + wc * 64 + (lane & 15);
#pragma unroll
  for (int fn = 0; fn < 4; ++fn) {
    const int col = col0 + fn * 16;
    const float s = scales[col];
    const float b = bias[col];
#pragma unroll
    for (int fm = 0; fm < 8; ++fm) {
      const int r0 = row0 + fm * 16;
#pragma unroll
      for (int r = 0; r < 4; ++r)
        out[(size_t)(r0 + r) * NN + col] = acc[fm][fn][r] * s + b;
    }
  }
}

// ---------------- fallback: fused convert-in-staging (if ws too small) ----------------
__device__ __forceinline__ void epilogue128(f32x4 acc[4][4],
                                            const float* __restrict__ scales,
                                            const float* __restrict__ bias,
                                            float* __restrict__ out,
                                            int bm, int bn, int lane, int wr, int wc) {
  const int row0 = bm * 128 + wr * 64 + ((lane >> 4) * 4);
  const int col0 = bn * 128 + wc * 64 + (lane & 15);
#pragma unroll
  for (int tn = 0; tn < 4; ++tn) {
    const int col = col0 + tn * 16;
    const float s = scales[col];
    const float b = bias[col];
#pragma unroll
    for (int tm = 0; tm < 4; ++tm) {
      const int r0 = row0 + tm * 16;
#pragma unroll
      for (int r = 0; r < 4; ++r)
        out[(long)(r0 + r) * NN + col] = acc[tm][tn][r] * s + b;
    }
  }
}

__global__ __launch_bounds__(256, 2) void gemm_fused_kernel(
    const float* __restrict__ A,   // [MM][KK] fp32
    const int* __restrict__ W32,   // [NN][KK] int32
    const float* __restrict__ scales,
    const float* __restrict__ bias,
    float* __restrict__ out) {
  __shared__ bf16 As[128 * 32];
  __shared__ bf16 Ws[128 * 32];
  const int tid  = threadIdx.x;
  const int lane = tid & 63;
  const int wave = tid >> 6;
  const int wr   = wave >> 1, wc = wave & 1;
  const int bm   = blockIdx.x, bn = blockIdx.y;

  f32x4 acc[4][4] = {};

  const int r    = tid >> 1;
  const int kk16 = (tid & 1) * 16;

  const float* Ag = A + (long)(bm * 128 + r) * KK + kk16;
  const int*   Wg = W32 + (long)(bn * 128 + r) * KK + kk16;
  bf16* Asw = As + r * 32 + kk16;
  bf16* Wsw = Ws + r * 32 + kk16;

  for (int k0 = 0; k0 < KK; k0 += 32) {
    float4 a0 = *(const float4*)(Ag + k0);
    float4 a1 = *(const float4*)(Ag + k0 + 4);
    float4 a2 = *(const float4*)(Ag + k0 + 8);
    float4 a3 = *(const float4*)(Ag + k0 + 12);
    int4 v0 = *(const int4*)(Wg + k0);
    int4 v1 = *(const int4*)(Wg + k0 + 4);
    int4 v2 = *(const int4*)(Wg + k0 + 8);
    int4 v3 = *(const int4*)(Wg + k0 + 12);
    __syncthreads();
    bf16x8 h0, h1, w0, w1;
    h0[0] = (bf16)a0.x; h0[1] = (bf16)a0.y; h0[2] = (bf16)a0.z; h0[3] = (bf16)a0.w;
    h0[4] = (bf16)a1.x; h0[5] = (bf16)a1.y; h0[6] = (bf16)a1.z; h0[7] = (bf16)a1.w;
    h1[0] = (bf16)a2.x; h1[1] = (bf16)a2.y; h1[2] = (bf16)a2.z; h1[3] = (bf16)a2.w;
    h1[4] = (bf16)a3.x; h1[5] = (bf16)a3.y; h1[6] = (bf16)a3.z; h1[7] = (bf16)a3.w;
    w0[0] = (bf16)(float)v0.x; w0[1] = (bf16)(float)v0.y;
    w0[2] = (bf16)(float)v0.z; w0[3] = (bf16)(float)v0.w;
    w0[4] = (bf16)(float)v1.x; w0[5] = (bf16)(float)v1.y;
    w0[6] = (bf16)(float)v1.z; w0[7] = (bf16)(float)v1.w;
    w1[0] = (bf16)(float)v2.x; w1[1] = (bf16)(float)v2.y;
    w1[2] = (bf16)(float)v2.z; w1[3] = (bf16)(float)v2.w;
    w1[4] = (bf16)(float)v3.x; w1[5] = (bf16)(float)v3.y;
    w1[6] = (bf16)(float)v3.z; w1[7] = (bf16)(float)v3.w;
    *(bf16x8*)(Asw)     = h0;
    *(bf16x8*)(Asw + 8) = h1;
    *(bf16x8*)(Wsw)     = w0;
    *(bf16x8*)(Wsw + 8) = w1;
    __syncthreads();
    const int m16 = lane & 15;
    const int ko  = (lane >> 4) * 8;
    bf16x8 af[4], bg[4];
#pragma unroll
    for (int t = 0; t < 4; ++t) {
      af[t] = *(const bf16x8*)(As + (wr * 64 + t * 16 + m16) * 32 + ko);
      bg[t] = *(const bf16x8*)(Ws + (wc * 64 + t * 16 + m16) * 32 + ko);
    }
#pragma unroll
    for (int tm = 0; tm < 4; ++tm)
#pragma unroll
      for (int tn = 0; tn < 4; ++tn)
        acc[tm][tn] = __builtin_amdgcn_mfma_f32_16x16x32_bf16(af[tm], bg[tn], acc[tm][tn], 0, 0, 0);
  }
  epilogue128(acc, scales, bias, out, bm, bn, lane, wr, wc);
}

// ---------------- launch ----------------
extern "C" void kernel_launch(void* const* d_in, const int* in_sizes, int n_in,
                              void* d_out, int out_size, void* d_ws, size_t ws_size,
                              hipStream_t stream) {
  const float* x      = (const float*)d_in[0];
  const int*   w32    = (const int*)d_in[1];
  const float* scales = (const float*)d_in[2];
  const float* bias   = (const float*)d_in[3];
  float*       out    = (float*)d_out;

  const size_t A_BYTES = (size_t)MM * KK * 2;  // 32 MiB
  const size_t W_BYTES = (size_t)NN * KK * 2;  // 86 MiB

  if (ws_size >= A_BYTES + W_BYTES) {
    static bool attr_done = false;
    if (!attr_done) {
      (void)hipFuncSetAttribute((const void*)gemm256_kernel,
                                hipFuncAttributeMaxDynamicSharedMemorySize, 131072);
      attr_done = true;
    }
    bf16* A16 = (bf16*)d_ws;
    bf16* W16 = (bf16*)((char*)d_ws + A_BYTES);
    const int na = MM * KK / 4;
    hipLaunchKernelGGL(cvt_a_kernel, dim3((na + 255) / 256), dim3(256), 0, stream, x, A16, na);
    const int nw = NN * KK / 4;
    hipLaunchKernelGGL(cvt_w_kernel, dim3((nw + 255) / 256), dim3(256), 0, stream, w32, W16, nw);
    hipLaunchKernelGGL(gemm256_kernel, dim3(MM / 256, NN / 256), dim3(512), 131072, stream,
                       A16, W16, scales, bias, out);
  } else {
    hipLaunchKernelGGL(gemm_fused_kernel, dim3(MM / 128, NN / 128), dim3(256), 0, stream,
                       x, w32, scales, bias, out);
  }
}

// Round 4
// 639.437 us; speedup vs baseline: 1.2298x; 1.0718x over previous
//
#include <hip/hip_runtime.h>
#include <stdint.h>

#define MM 4096   // B*S
#define KK 4096   // IN_F
#define NN 11008  // OUT_F
#define NK 64     // KK/64 K-steps of the 256^2 kernel

typedef __bf16 bf16;
typedef bf16 bf16x8 __attribute__((ext_vector_type(8)));
typedef float f32x4 __attribute__((ext_vector_type(4)));

static_assert(sizeof(bf16x8) == 16, "bf16x8 must be 16B");

// ---------------- async global->LDS (width 16) ----------------
__device__ __forceinline__ void async_ld16(const void* g, void* l) {
  __builtin_amdgcn_global_load_lds(
      (const __attribute__((address_space(1))) uint32_t*)g,
      (__attribute__((address_space(3))) uint32_t*)l,
      16, 0, 0);
}

// ---------------- convert kernels ----------------
__global__ __launch_bounds__(256) void cvt_a_kernel(const float* __restrict__ in,
                                                    bf16* __restrict__ out, int n4) {
  int i = blockIdx.x * 256 + threadIdx.x;
  if (i >= n4) return;
  float4 v = ((const float4*)in)[i];
  union { bf16 h[4]; uint2 u; } p;
  p.h[0] = (bf16)v.x; p.h[1] = (bf16)v.y; p.h[2] = (bf16)v.z; p.h[3] = (bf16)v.w;
  ((uint2*)out)[i] = p.u;
}

// weights land as int32 (harness integer contract; absmax=256 path passes).
__global__ __launch_bounds__(256) void cvt_w_kernel(const int* __restrict__ in,
                                                    bf16* __restrict__ out, int n4) {
  int i = blockIdx.x * 256 + threadIdx.x;
  if (i >= n4) return;
  int4 v = ((const int4*)in)[i];
  union { bf16 h[4]; uint2 u; } p;
  p.h[0] = (bf16)(float)v.x; p.h[1] = (bf16)(float)v.y;
  p.h[2] = (bf16)(float)v.z; p.h[3] = (bf16)(float)v.w;
  ((uint2*)out)[i] = p.u;
}

// =====================================================================
// 256x256 GEMM, 2-barrier K-step (R3 structure) + FULL T2 swizzle (R4)
//
// R3 POST-MORTEM: kernel sits exactly at the conflict-implied LDS-read
// ceiling: 4 extra cyc/read (3.38e7 / 8.45e6 reads) -> 1536 cyc LDS vs
// 620 cyc MFMA per K-step per CU -> 40% MfmaUtil cap; measured 38-41.
//
// R4 CHANGE (swizzle only): catalog-verbatim T2 recipe,
//   lds[row][col ^ ((row&7)<<3)]   (elements; = byte ^ ((row&7)<<4))
// XOR the FULL 3-bit 16B-slot index with row bits 0-2 (R1/R2 each only
// XORed one bit -> 2 of 8 slots -> residual 2x penalty). For all A/B
// fragment reads row&7 == lane&7 (wr*128, wc*64, fm*16 are 0 mod 8), so
// each 8-lane row group spreads across all 8 slots.
//   - write: global_load_lds dest LINEAR (rule #21); thread tid writes
//     (row tid>>3, 16B-group tid&7) -> global source k-group
//     (tid&7) ^ ((tid>>3)&7).
//   - read: 16B-group (kc*4 + (lane>>4)) ^ (lane&7).
// Involution: content[r][g] = global[r][g^(r&7)]; reading at
// g_log^(r&7) yields global[r][g_log].  XOR stays within each 128B row
// segment -> global coalescing preserved.
//
// Sync structure (R3, unchanged): 2 barriers/K-step; all 24 ds_reads up
// front (compiler emits counted lgkmcnt); stage (c+1).B1/A1 [other buf];
// q0,q1 MFMA; lgkmcnt(0)+raw barrier; stage (c+2).B0/A0 [this buf];
// q2,q3 MFMA; boundary vmcnt(4) (T4, never 0 in hot loop); barrier.
// Tail: last two K-steps peeled; NK-2 boundary vmcnt(0).
// =====================================================================
__global__ __launch_bounds__(512, 2) void gemm256_kernel(
    const bf16* __restrict__ A,   // [MM][KK] bf16
    const bf16* __restrict__ W,   // [NN][KK] bf16 (B^T layout)
    const float* __restrict__ scales,
    const float* __restrict__ bias,
    float* __restrict__ out) {
  extern __shared__ bf16 lds[];
  bf16* LA = lds;               // [2][256][64]
  bf16* LB = lds + 2 * 16384;   // [2][256][64]

  const int tid  = threadIdx.x;
  const int lane = tid & 63;
  const int wave = tid >> 6;          // 0..7
  const int wr   = wave >> 2;         // 0..1  (M half)
  const int wc   = wave & 3;          // 0..3  (N quarter)

  // T1: bijective XCD swizzle. nwg = 16*43 = 688 = 8*86 exactly.
  const int flat = blockIdx.y * 16 + blockIdx.x;
  const int swz  = (flat & 7) * 86 + (flat >> 3);
  const int bm   = swz & 15;   // 0..15
  const int bn   = swz >> 4;   // 0..42

  // staging source mapping: inverse of full T2 swizzle.
  // thread tid writes (row tid>>3, group tid&7) -> fetch group g^ (row&7)
  const int srow = tid >> 3;                                  // 0..63
  const int skel = (((tid & 7) ^ ((tid >> 3) & 7)) * 8);      // pre-swizzled k element
  const bf16* gA = A + (size_t)(bm * 256 + srow) * KK + skel;
  const bf16* gW = W + (size_t)(bn * 256 + srow) * KK + skel;

  // ds_read per-lane element offsets (full T2 swizzle)
  const int m16  = lane & 15;
  const int s3   = lane & 7;                         // row&7 key
  const int ke0  = (((lane >> 4)) ^ s3) * 8;         // logical kc=0 group
  const int ke1  = ((4 + (lane >> 4)) ^ s3) * 8;     // logical kc=1 group
  const int aRow = wr * 128 + m16;
  const int bRow = wc * 64 + m16;

  f32x4 acc[8][4] = {};

  auto stage_half = [&](const bf16* g, bf16* l) {
    async_ld16(g, l + wave * 512);
    async_ld16(g + (size_t)64 * KK, l + 64 * 64 + wave * 512);
  };

  // ---- prologue: K0 fully + K1 first 2 half-tiles ----
  stage_half(gW,                    LB);             // K0.B0
  stage_half(gA,                    LA);             // K0.A0
  stage_half(gW + (size_t)128 * KK, LB + 128 * 64);  // K0.B1
  stage_half(gA + (size_t)128 * KK, LA + 128 * 64);  // K0.A1
  stage_half(gW + 64,               LB + 16384);     // K1.B0
  stage_half(gA + 64,               LA + 16384);     // K1.A0
  asm volatile("s_waitcnt vmcnt(4)" ::: "memory");   // K0 landed; K1.B0/A0 in flight
  __builtin_amdgcn_s_barrier();

  // ---- one K-step (s1: stage c+1 halves, s2: stage c+2 halves) ----
  auto kstep = [&](int c, bool s1, bool s2, bool tail) {
    const int cb = c & 1;
    const bf16* At = LA + cb * 16384;          // K-step c (read)
    const bf16* Wt = LB + cb * 16384;
    bf16* An = LA + (cb ^ 1) * 16384;          // K-step c+1 (stage, other buf)
    bf16* Bn = LB + (cb ^ 1) * 16384;
    bf16* Ac = LA + cb * 16384;                // K-step c+2 (stage, this buf)
    bf16* Bc = LB + cb * 16384;
    const size_t k1 = (size_t)(c + 1) * 64;
    const size_t k2 = (size_t)(c + 2) * 64;

    bf16x8 aLo[4][2], aHi[4][2], bLo[2][2], bHi[2][2];

    // all 24 fragment reads up front; compiler emits counted lgkmcnt
#pragma unroll
    for (int fm = 0; fm < 4; ++fm) {
      aLo[fm][0] = *(const bf16x8*)(At + (aRow + fm * 16) * 64 + ke0);
      aLo[fm][1] = *(const bf16x8*)(At + (aRow + fm * 16) * 64 + ke1);
    }
#pragma unroll
    for (int fn = 0; fn < 2; ++fn) {
      bLo[fn][0] = *(const bf16x8*)(Wt + (bRow + fn * 16) * 64 + ke0);
      bLo[fn][1] = *(const bf16x8*)(Wt + (bRow + fn * 16) * 64 + ke1);
    }
#pragma unroll
    for (int fn = 0; fn < 2; ++fn) {
      bHi[fn][0] = *(const bf16x8*)(Wt + (bRow + (fn + 2) * 16) * 64 + ke0);
      bHi[fn][1] = *(const bf16x8*)(Wt + (bRow + (fn + 2) * 16) * 64 + ke1);
    }
#pragma unroll
    for (int fm = 0; fm < 4; ++fm) {
      aHi[fm][0] = *(const bf16x8*)(At + (aRow + (fm + 4) * 16) * 64 + ke0);
      aHi[fm][1] = *(const bf16x8*)(At + (aRow + (fm + 4) * 16) * 64 + ke1);
    }

    if (s1) {
      stage_half(gW + (size_t)128 * KK + k1, Bn + 128 * 64);  // (c+1).B1
      stage_half(gA + (size_t)128 * KK + k1, An + 128 * 64);  // (c+1).A1
    }

    __builtin_amdgcn_s_setprio(1);
#pragma unroll
    for (int fm = 0; fm < 4; ++fm)        // q0: mLo x nLo
#pragma unroll
      for (int fn = 0; fn < 2; ++fn)
#pragma unroll
        for (int kc = 0; kc < 2; ++kc)
          acc[fm][fn] = __builtin_amdgcn_mfma_f32_16x16x32_bf16(aLo[fm][kc], bLo[fn][kc], acc[fm][fn], 0, 0, 0);
#pragma unroll
    for (int fm = 0; fm < 4; ++fm)        // q1: mLo x nHi
#pragma unroll
      for (int fn = 0; fn < 2; ++fn)
#pragma unroll
        for (int kc = 0; kc < 2; ++kc)
          acc[fm][fn + 2] = __builtin_amdgcn_mfma_f32_16x16x32_bf16(aLo[fm][kc], bHi[fn][kc], acc[fm][fn + 2], 0, 0, 0);
    __builtin_amdgcn_s_setprio(0);

    // all waves done reading buffer c (raw barrier: vmcnt stays in flight)
    asm volatile("s_waitcnt lgkmcnt(0)" ::: "memory");
    __builtin_amdgcn_s_barrier();

    if (s2) {
      stage_half(gW + k2, Bc);                                // (c+2).B0
      stage_half(gA + k2, Ac);                                // (c+2).A0
    }

    __builtin_amdgcn_s_setprio(1);
#pragma unroll
    for (int fm = 0; fm < 4; ++fm)        // q2: mHi x nLo
#pragma unroll
      for (int fn = 0; fn < 2; ++fn)
#pragma unroll
        for (int kc = 0; kc < 2; ++kc)
          acc[fm + 4][fn] = __builtin_amdgcn_mfma_f32_16x16x32_bf16(aHi[fm][kc], bLo[fn][kc], acc[fm + 4][fn], 0, 0, 0);
#pragma unroll
    for (int fm = 0; fm < 4; ++fm)        // q3: mHi x nHi
#pragma unroll
      for (int fn = 0; fn < 2; ++fn)
#pragma unroll
        for (int kc = 0; kc < 2; ++kc)
          acc[fm + 4][fn + 2] = __builtin_amdgcn_mfma_f32_16x16x32_bf16(aHi[fm][kc], bHi[fn][kc], acc[fm + 4][fn + 2], 0, 0, 0);
    __builtin_amdgcn_s_setprio(0);

    // K-step boundary: counted wait (T4); vmcnt(0) only at the tail.
    if (!tail) asm volatile("s_waitcnt vmcnt(4)" ::: "memory");
    else       asm volatile("s_waitcnt vmcnt(0)" ::: "memory");
    __builtin_amdgcn_s_barrier();
  };

  for (int c = 0; c < NK - 2; ++c) kstep(c, true, true, false);
  kstep(NK - 2, true, false, true);   // vmcnt(0): (NK-1).B1/A1 must land
  kstep(NK - 1, false, false, true);

  // ---------- epilogue ----------
  const int row0 = bm * 256 + wr * 128 + ((lane >> 4) * 4);
  const int col0 = bn * 256 + wc * 64 + (lane & 15);
#pragma unroll
  for (int fn = 0; fn < 4; ++fn) {
    const int col = col0 + fn * 16;
    const float s = scales[col];
    const float b = bias[col];
#pragma unroll
    for (int fm = 0; fm < 8; ++fm) {
      const int r0 = row0 + fm * 16;
#pragma unroll
      for (int r = 0; r < 4; ++r)
        out[(size_t)(r0 + r) * NN + col] = acc[fm][fn][r] * s + b;
    }
  }
}

// ---------------- fallback: fused convert-in-staging (if ws too small) ----------------
__device__ __forceinline__ void epilogue128(f32x4 acc[4][4],
                                            const float* __restrict__ scales,
                                            const float* __restrict__ bias,
                                            float* __restrict__ out,
                                            int bm, int bn, int lane, int wr, int wc) {
  const int row0 = bm * 128 + wr * 64 + ((lane >> 4) * 4);
  const int col0 = bn * 128 + wc * 64 + (lane & 15);
#pragma unroll
  for (int tn = 0; tn < 4; ++tn) {
    const int col = col0 + tn * 16;
    const float s = scales[col];
    const float b = bias[col];
#pragma unroll
    for (int tm = 0; tm < 4; ++tm) {
      const int r0 = row0 + tm * 16;
#pragma unroll
      for (int r = 0; r < 4; ++r)
        out[(long)(r0 + r) * NN + col] = acc[tm][tn][r] * s + b;
    }
  }
}

__global__ __launch_bounds__(256, 2) void gemm_fused_kernel(
    const float* __restrict__ A,   // [MM][KK] fp32
    const int* __restrict__ W32,   // [NN][KK] int32
    const float* __restrict__ scales,
    const float* __restrict__ bias,
    float* __restrict__ out) {
  __shared__ bf16 As[128 * 32];
  __shared__ bf16 Ws[128 * 32];
  const int tid  = threadIdx.x;
  const int lane = tid & 63;
  const int wave = tid >> 6;
  const int wr   = wave >> 1, wc = wave & 1;
  const int bm   = blockIdx.x, bn = blockIdx.y;

  f32x4 acc[4][4] = {};

  const int r    = tid >> 1;
  const int kk16 = (tid & 1) * 16;

  const float* Ag = A + (long)(bm * 128 + r) * KK + kk16;
  const int*   Wg = W32 + (long)(bn * 128 + r) * KK + kk16;
  bf16* Asw = As + r * 32 + kk16;
  bf16* Wsw = Ws + r * 32 + kk16;

  for (int k0 = 0; k0 < KK; k0 += 32) {
    float4 a0 = *(const float4*)(Ag + k0);
    float4 a1 = *(const float4*)(Ag + k0 + 4);
    float4 a2 = *(const float4*)(Ag + k0 + 8);
    float4 a3 = *(const float4*)(Ag + k0 + 12);
    int4 v0 = *(const int4*)(Wg + k0);
    int4 v1 = *(const int4*)(Wg + k0 + 4);
    int4 v2 = *(const int4*)(Wg + k0 + 8);
    int4 v3 = *(const int4*)(Wg + k0 + 12);
    __syncthreads();
    bf16x8 h0, h1, w0, w1;
    h0[0] = (bf16)a0.x; h0[1] = (bf16)a0.y; h0[2] = (bf16)a0.z; h0[3] = (bf16)a0.w;
    h0[4] = (bf16)a1.x; h0[5] = (bf16)a1.y; h0[6] = (bf16)a1.z; h0[7] = (bf16)a1.w;
    h1[0] = (bf16)a2.x; h1[1] = (bf16)a2.y; h1[2] = (bf16)a2.z; h1[3] = (bf16)a2.w;
    h1[4] = (bf16)a3.x; h1[5] = (bf16)a3.y; h1[6] = (bf16)a3.z; h1[7] = (bf16)a3.w;
    w0[0] = (bf16)(float)v0.x; w0[1] = (bf16)(float)v0.y;
    w0[2] = (bf16)(float)v0.z; w0[3] = (bf16)(float)v0.w;
    w0[4] = (bf16)(float)v1.x; w0[5] = (bf16)(float)v1.y;
    w0[6] = (bf16)(float)v1.z; w0[7] = (bf16)(float)v1.w;
    w1[0] = (bf16)(float)v2.x; w1[1] = (bf16)(float)v2.y;
    w1[2] = (bf16)(float)v2.z; w1[3] = (bf16)(float)v2.w;
    w1[4] = (bf16)(float)v3.x; w1[5] = (bf16)(float)v3.y;
    w1[6] = (bf16)(float)v3.z; w1[7] = (bf16)(float)v3.w;
    *(bf16x8*)(Asw)     = h0;
    *(bf16x8*)(Asw + 8) = h1;
    *(bf16x8*)(Wsw)     = w0;
    *(bf16x8*)(Wsw + 8) = w1;
    __syncthreads();
    const int m16 = lane & 15;
    const int ko  = (lane >> 4) * 8;
    bf16x8 af[4], bg[4];
#pragma unroll
    for (int t = 0; t < 4; ++t) {
      af[t] = *(const bf16x8*)(As + (wr * 64 + t * 16 + m16) * 32 + ko);
      bg[t] = *(const bf16x8*)(Ws + (wc * 64 + t * 16 + m16) * 32 + ko);
    }
#pragma unroll
    for (int tm = 0; tm < 4; ++tm)
#pragma unroll
      for (int tn = 0; tn < 4; ++tn)
        acc[tm][tn] = __builtin_amdgcn_mfma_f32_16x16x32_bf16(af[tm], bg[tn], acc[tm][tn], 0, 0, 0);
  }
  epilogue128(acc, scales, bias, out, bm, bn, lane, wr, wc);
}

// ---------------- launch ----------------
extern "C" void kernel_launch(void* const* d_in, const int* in_sizes, int n_in,
                              void* d_out, int out_size, void* d_ws, size_t ws_size,
                              hipStream_t stream) {
  const float* x      = (const float*)d_in[0];
  const int*   w32    = (const int*)d_in[1];
  const float* scales = (const float*)d_in[2];
  const float* bias   = (const float*)d_in[3];
  float*       out    = (float*)d_out;

  const size_t A_BYTES = (size_t)MM * KK * 2;  // 32 MiB
  const size_t W_BYTES = (size_t)NN * KK * 2;  // 86 MiB

  if (ws_size >= A_BYTES + W_BYTES) {
    static bool attr_done = false;
    if (!attr_done) {
      (void)hipFuncSetAttribute((const void*)gemm256_kernel,
                                hipFuncAttributeMaxDynamicSharedMemorySize, 131072);
      attr_done = true;
    }
    bf16* A16 = (bf16*)d_ws;
    bf16* W16 = (bf16*)((char*)d_ws + A_BYTES);
    const int na = MM * KK / 4;
    hipLaunchKernelGGL(cvt_a_kernel, dim3((na + 255) / 256), dim3(256), 0, stream, x, A16, na);
    const int nw = NN * KK / 4;
    hipLaunchKernelGGL(cvt_w_kernel, dim3((nw + 255) / 256), dim3(256), 0, stream, w32, W16, nw);
    hipLaunchKernelGGL(gemm256_kernel, dim3(MM / 256, NN / 256), dim3(512), 131072, stream,
                       A16, W16, scales, bias, out);
  } else {
    hipLaunchKernelGGL(gemm_fused_kernel, dim3(MM / 128, NN / 128), dim3(256), 0, stream,
                       x, w32, scales, bias, out);
  }
}